// Round 8
// baseline (200.481 us; speedup 1.0000x reference)
//
#include <hip/hip_runtime.h>
#include <hip/hip_bf16.h>
#include <stdint.h>
#include <stddef.h>

typedef __bf16 bf16_t;
typedef __bf16 bf16x4 __attribute__((ext_vector_type(4)));
typedef __bf16 bf16x8 __attribute__((ext_vector_type(8)));
typedef float f32x4 __attribute__((ext_vector_type(4)));
typedef float f32x16 __attribute__((ext_vector_type(16)));

#define MFMA16(a, b, c) __builtin_amdgcn_mfma_f32_16x16x32_bf16(a, b, c, 0, 0, 0)
#define MFMA32(a, b, c) __builtin_amdgcn_mfma_f32_32x32x16_bf16(a, b, c, 0, 0, 0)

// async global->LDS, 16 B per lane; LDS dest = uniform base + lane*16
#define GLL16(g, l)                                                      \
    __builtin_amdgcn_global_load_lds(                                    \
        (const __attribute__((address_space(1))) void*)(g),              \
        (__attribute__((address_space(3))) void*)(l), 16, 0, 0)

#define SEQ 2048
#define NHEAD 16
#define HD 64
#define HID 1024
#define QKV_LD 3072
#define VT_LD 2080  // 2048 + 32 pad: breaks 4 KB power-of-2 L2 set aliasing

// ---------------------------------------------------------------------------
// Fused prep: cast x -> bf16 (blocks 0..4095), transpose+cast w_qkv
// (4096..7167), transpose+cast w_out (7168..8191).
// ---------------------------------------------------------------------------
__global__ __launch_bounds__(256)
void prep_kernel(const float* __restrict__ x, const float* __restrict__ w_qkv,
                 const float* __restrict__ w_out, bf16_t* __restrict__ xbf,
                 bf16_t* __restrict__ wqkvT, bf16_t* __restrict__ woutT) {
    int L = blockIdx.x;
    int tid = threadIdx.x;
    if (L < 4096) {  // cast x
        int i = (L * 256 + tid) * 4;
        float4 v = *(const float4*)(x + i);
        bf16x4 o = {(bf16_t)v.x, (bf16_t)v.y, (bf16_t)v.z, (bf16_t)v.w};
        *(bf16x4*)(xbf + i) = o;
        return;
    }
    __shared__ bf16_t tile[32][33];
    const float* W;
    bf16_t* Wt;
    int N, bx, by;
    if (L < 7168) {
        int r = L - 4096;
        W = w_qkv; Wt = wqkvT; N = 3072; bx = r % 96; by = r / 96;
    } else {
        int r = L - 7168;
        W = w_out; Wt = woutT; N = 1024; bx = r % 32; by = r / 32;
    }
    int K = 1024;
    int n0 = bx * 32, k0 = by * 32;
    int tx = tid & 31, ty = tid >> 5;  // 32 x 8
#pragma unroll
    for (int i = 0; i < 4; i++)
        tile[ty + i * 8][tx] = (bf16_t)W[(size_t)(k0 + ty + i * 8) * N + n0 + tx];
    __syncthreads();
#pragma unroll
    for (int i = 0; i < 4; i++)
        Wt[(size_t)(n0 + ty + i * 8) * K + k0 + tx] = tile[tx][ty + i * 8];
}

// ---------------------------------------------------------------------------
// QKV GEMM, 256x256 tile, BK=64, 8-phase + deep staging.  FROZEN (control):
// five variants (2-barrier/128^2, 8-phase, 1-barrier, deep-staged, + R0's
// BK=32 3-blk/CU) all measured 42.5-44.2 us / MfmaUtil 20-23%.  Diagnosis:
// LDS-read-issue bound -- 192 wave b128 reads/tile ~2300 cyc vs 620 cyc
// MFMA -> ~27% ceiling; matches measurement.  Scheduling can't fix that
// without a different fragment decomposition; frozen.
// ---------------------------------------------------------------------------
#define STAGE8(GB, LB, KOFF)                                                   \
    do {                                                                       \
        GLL16((GB) + (size_t)srow * K + (KOFF) + ssw,                          \
              (LB) + srow * 64 + (scl << 3));                                  \
        GLL16((GB) + (size_t)(srow + 64) * K + (KOFF) + ssw,                   \
              (LB) + (srow + 64) * 64 + (scl << 3));                           \
    } while (0)

// stage a full 256x64 A-tile + 256x64 B-tile (8 GLL16/wave) into buffer BUF
#define STAGE_ALL(ASB, BSB, KOFF)                                              \
    do {                                                                       \
        STAGE8(Bb, (BSB), KOFF);                                               \
        STAGE8(Ab, (ASB), KOFF);                                               \
        STAGE8(Bb + (size_t)128 * K, (BSB) + 128 * 64, KOFF);                  \
        STAGE8(Ab + (size_t)128 * K, (ASB) + 128 * 64, KOFF);                  \
    } while (0)

__global__ __launch_bounds__(512, 2)
void gemm_qkv_8ph(const bf16_t* __restrict__ A, const bf16_t* __restrict__ Bt,
                  const float* __restrict__ bias, bf16_t* __restrict__ C,
                  bf16_t* __restrict__ Vt, int M, int N, int K) {
    __shared__ __align__(16) bf16_t As[2][256][64];
    __shared__ __align__(16) bf16_t Bs[2][256][64];

    // T1: bijective XCD swizzle (gridDim.x % 8 == 0)
    int nbx = N >> 8;
    int bid = blockIdx.x;
    int swz = (bid & 7) * (gridDim.x >> 3) + (bid >> 3);
    int m0 = (swz / nbx) << 8;
    int n0 = (swz % nbx) << 8;

    int tid = threadIdx.x;
    int lane = tid & 63;
    int wave = tid >> 6;
    int l16 = lane & 15, quad = lane >> 4;
    int wm = (wave >> 2) << 7;  // 0 / 128
    int wn = (wave & 3) << 6;   // 0 / 64 / 128 / 192

    // staging coords: 512 thr x 16 B = one 64-row sweep; 8 chunks/row
    int srow = tid >> 3;  // 0..63
    int scl = tid & 7;
    int ssw = ((scl ^ (srow & 7)) << 3);  // pre-swizzled global chunk offset

    const bf16_t* Ab = A + (size_t)m0 * K;
    const bf16_t* Bb = Bt + (size_t)n0 * K;

    f32x4 acc[8][4] = {};  // [msub*4+mt][nsub*2+nt]
    bf16x8 a[4][2], b0[2][2], b1[2][2];

    const int NT = K >> 6;  // 16 K-tiles of 64

    // ---- prologue: burst-stage tile0 -> buf0, tile1 -> buf1; drain t0 ----
    STAGE_ALL(&As[0][0][0], &Bs[0][0][0], 0);
    STAGE_ALL(&As[1][0][0], &Bs[1][0][0], 64);
    asm volatile("s_waitcnt vmcnt(8)" ::: "memory");
    __builtin_amdgcn_s_barrier();

    for (int t = 0; t < NT; t++) {
        int buf = t & 1;
        const bf16_t* Asb = &As[buf][0][0];
        const bf16_t* Bsb = &Bs[buf][0][0];
        int k2 = (t + 2) << 6;

        // ===== phase 1: read A0 (msub0) + B0 (nsub0); P0 MFMA =====
#pragma unroll
        for (int mt = 0; mt < 4; mt++) {
            int row = wm + mt * 16 + l16;
#pragma unroll
            for (int ks = 0; ks < 2; ks++)
                a[mt][ks] = *(const bf16x8*)(
                    Asb + row * 64 + (((ks * 4 + quad) ^ (row & 7)) << 3));
        }
#pragma unroll
        for (int nt = 0; nt < 2; nt++) {
            int row = wn + nt * 16 + l16;
#pragma unroll
            for (int ks = 0; ks < 2; ks++)
                b0[nt][ks] = *(const bf16x8*)(
                    Bsb + row * 64 + (((ks * 4 + quad) ^ (row & 7)) << 3));
        }
        __builtin_amdgcn_s_barrier();
        asm volatile("s_waitcnt lgkmcnt(0)" ::: "memory");
        __builtin_amdgcn_s_setprio(1);
#pragma unroll
        for (int mt = 0; mt < 4; mt++)
#pragma unroll
            for (int nt = 0; nt < 2; nt++)
#pragma unroll
                for (int ks = 0; ks < 2; ks++)
                    acc[mt][nt] = MFMA16(a[mt][ks], b0[nt][ks], acc[mt][nt]);
        __builtin_amdgcn_s_setprio(0);
        __builtin_amdgcn_s_barrier();

        // ===== phase 2: read B1 (nsub1); P1 MFMA =====
#pragma unroll
        for (int nt = 0; nt < 2; nt++) {
            int row = wn + 32 + nt * 16 + l16;
#pragma unroll
            for (int ks = 0; ks < 2; ks++)
                b1[nt][ks] = *(const bf16x8*)(
                    Bsb + row * 64 + (((ks * 4 + quad) ^ (row & 7)) << 3));
        }
        __builtin_amdgcn_s_barrier();
        asm volatile("s_waitcnt lgkmcnt(0)" ::: "memory");
        __builtin_amdgcn_s_setprio(1);
#pragma unroll
        for (int mt = 0; mt < 4; mt++)
#pragma unroll
            for (int nt = 0; nt < 2; nt++)
#pragma unroll
                for (int ks = 0; ks < 2; ks++)
                    acc[mt][2 + nt] =
                        MFMA16(a[mt][ks], b1[nt][ks], acc[mt][2 + nt]);
        __builtin_amdgcn_s_setprio(0);
        __builtin_amdgcn_s_barrier();

        // ===== phase 3: read A1 (msub1); P2 MFMA =====
#pragma unroll
        for (int mt = 0; mt < 4; mt++) {
            int row = wm + 64 + mt * 16 + l16;
#pragma unroll
            for (int ks = 0; ks < 2; ks++)
                a[mt][ks] = *(const bf16x8*)(
                    Asb + row * 64 + (((ks * 4 + quad) ^ (row & 7)) << 3));
        }
        __builtin_amdgcn_s_barrier();
        asm volatile("s_waitcnt lgkmcnt(0)" ::: "memory");
        __builtin_amdgcn_s_setprio(1);
#pragma unroll
        for (int mt = 0; mt < 4; mt++)
#pragma unroll
            for (int nt = 0; nt < 2; nt++)
#pragma unroll
                for (int ks = 0; ks < 2; ks++)
                    acc[4 + mt][nt] =
                        MFMA16(a[mt][ks], b0[nt][ks], acc[4 + mt][nt]);
        __builtin_amdgcn_s_setprio(0);
        __builtin_amdgcn_s_barrier();

        // ===== phase 4: burst-stage t+2 -> current buf; counted drain; P3 ===
        if (t + 2 < NT) {
            STAGE_ALL(&As[buf][0][0], &Bs[buf][0][0], k2);
            // completes exactly tile t+1's 8 loads (issued 4 phases ago)
            asm volatile("s_waitcnt vmcnt(8)" ::: "memory");
        } else if (t + 1 < NT) {
            asm volatile("s_waitcnt vmcnt(0)" ::: "memory");
        }
        __builtin_amdgcn_s_setprio(1);
#pragma unroll
        for (int mt = 0; mt < 4; mt++)
#pragma unroll
            for (int nt = 0; nt < 2; nt++)
#pragma unroll
                for (int ks = 0; ks < 2; ks++)
                    acc[4 + mt][2 + nt] =
                        MFMA16(a[mt][ks], b1[nt][ks], acc[4 + mt][2 + nt]);
        __builtin_amdgcn_s_setprio(0);
        __builtin_amdgcn_s_barrier();
    }

    // ---- epilogue.  C/D: col=l16, row=quad*4+reg ----
    if (n0 < 2048) {
        // Q/K tiles: normal qkv store
#pragma unroll
        for (int mi = 0; mi < 8; mi++) {
            int row = m0 + wm + (mi >> 2) * 64 + (mi & 3) * 16 + quad * 4;
#pragma unroll
            for (int ni = 0; ni < 4; ni++) {
                int col = n0 + wn + (ni >> 1) * 32 + (ni & 1) * 16 + l16;
                float bv = bias[col];
#pragma unroll
                for (int r = 0; r < 4; r++)
                    C[(size_t)(row + r) * N + col] = (bf16_t)(acc[mi][ni][r] + bv);
            }
        }
    } else {
        // V tiles: transposed store into Vt[bh][d][s] (qkv V region unused)
#pragma unroll
        for (int mi = 0; mi < 8; mi++) {
            int row = m0 + wm + (mi >> 2) * 64 + (mi & 3) * 16 + quad * 4;
            int b = row >> 11, s = row & 2047;
#pragma unroll
            for (int ni = 0; ni < 4; ni++) {
                int col = n0 + wn + (ni >> 1) * 32 + (ni & 1) * 16 + l16;
                float bv = bias[col];
                int cv = col - 2048;
                int bh = b * 16 + (cv >> 6);
                bf16x4 pk;
#pragma unroll
                for (int r = 0; r < 4; r++)
                    pk[r] = (bf16_t)(acc[mi][ni][r] + bv);
                *(bf16x4*)(Vt + ((size_t)bh * HD + (cv & 63)) * VT_LD + s) = pk;
            }
        }
    }
}

// ---------------------------------------------------------------------------
// GEMM: C[M][N] = A[M][K] @ Bt[N][K]^T + bias[N].  bf16, fp32 accum, OutT out.
// 128xTN tile, BK=32, 256 thr, GLL width-16 staging into unpadded LDS.
// Out-projection TN=128: grid (8,32)=256 blocks (100% CU).
// ---------------------------------------------------------------------------
template <typename OutT, int TN>
__global__ __launch_bounds__(256)
void gemm_bt_bias(const bf16_t* __restrict__ A, const bf16_t* __restrict__ Bt,
                  const float* __restrict__ bias, OutT* __restrict__ C,
                  int M, int N, int K) {
    constexpr int NT = TN / 32;  // acc n-tiles per wave
    __shared__ __align__(16) bf16_t As[128][32];
    __shared__ __align__(16) bf16_t Bs[TN][32];

    int m0 = blockIdx.y * 128;
    int n0 = blockIdx.x * TN;
    int tid = threadIdx.x;
    int wave = tid >> 6, lane = tid & 63;
    int quad = lane >> 4, l16 = lane & 15;
    int wm = (wave >> 1) * 64, wn = (wave & 1) * (TN / 2);

    f32x4 acc[4][NT] = {};

    const bf16_t* a_base =
        A + (size_t)(m0 + wave * 32 + (lane >> 2)) * K + (lane & 3) * 8;
    const bf16_t* b_base =
        Bt + (size_t)(n0 + wave * (TN / 4) + (lane >> 2)) * K + (lane & 3) * 8;
    bf16_t* as_base = &As[wave * 32][0];
    bf16_t* bs_base = &Bs[wave * (TN / 4)][0];

    for (int k0 = 0; k0 < K; k0 += 32) {
        GLL16(a_base + k0, as_base);
        GLL16(a_base + 16 * K + k0, as_base + 16 * 32);
        GLL16(b_base + k0, bs_base);
        if (TN == 128) GLL16(b_base + 16 * K + k0, bs_base + 16 * 32);
        __syncthreads();

        bf16x8 af[4], bfr[NT];
#pragma unroll
        for (int t = 0; t < 4; t++)
            af[t] = *(const bf16x8*)(&As[wm + t * 16 + l16][quad * 8]);
#pragma unroll
        for (int t = 0; t < NT; t++)
            bfr[t] = *(const bf16x8*)(&Bs[wn + t * 16 + l16][quad * 8]);
#pragma unroll
        for (int mt = 0; mt < 4; mt++)
#pragma unroll
            for (int nt = 0; nt < NT; nt++)
                acc[mt][nt] = MFMA16(af[mt], bfr[nt], acc[mt][nt]);
        __syncthreads();
    }

#pragma unroll
    for (int mt = 0; mt < 4; mt++) {
        int row = m0 + wm + mt * 16 + quad * 4;
#pragma unroll
        for (int nt = 0; nt < NT; nt++) {
            int col = n0 + wn + nt * 16 + l16;
            float bv = bias[col];
#pragma unroll
            for (int r = 0; r < 4; r++)
                C[(size_t)(row + r) * N + col] = (OutT)(acc[mt][nt][r] + bv);
        }
    }
}

// ---------------------------------------------------------------------------
// Attention, mask j >= i, mfma_f32_32x32x16_bf16.  TI=128, BJ=64, 8 waves
// (ih=w>>1 = i 32-block, jh=w&1 = j half).  P in registers (R7).
//
// ROUND-8: K DIRECT-FROM-GLOBAL.  The ka fragment (row j0+jh*32+l32, col
// ks*16+hi*8) is wave-private -- nothing is shared through LDS, so the
// global->reg->LDS->reg round trip for K was pure overhead on the dominant
// LDS issue pipe (~14 ops/wave/iter, vs ~130 cyc of MFMA).  Direct bf16x8
// global loads give the identical fragment; K is L2-hot (XCD-pinned bh,
// 256 KB/bh panel, ~2 MB/XCD << 4 MB L2); loads issue BEFORE the two
// V-staging barriers, which hide the ~200 cyc L2 latency.  Removes the Ks
// LDS array, kr prefetch reg, 1 staging write and 4 ds_reads per wave-iter
// (LDS ops 14 -> 9).  V stays in LDS (genuinely shared across ih-waves).
// Fragment mapping: A/B[m|n = lane&31][k = (lane>>5)*8 + e];
// C/D: col = lane&31, row = (reg&3) + 8*(reg>>2) + 4*(lane>>5)  [m74/m101].
// ---------------------------------------------------------------------------
__global__ __launch_bounds__(512, 4)
void attn_kernel(const bf16_t* __restrict__ qkv, const bf16_t* __restrict__ Vt,
                 bf16_t* __restrict__ attn_out) {
    int bh = blockIdx.x;        // linear%8 == bh%8 -> XCD pin
    int tile = (blockIdx.y < 8) ? blockIdx.y : (23 - blockIdx.y);
    int b = bh >> 4, h = bh & 15;

    int tid = threadIdx.x, wave = tid >> 6, lane = tid & 63;
    int l32 = lane & 31, hi = lane >> 5;
    int ih = wave >> 1, jh = wave & 1;

    const bf16_t* q_g = qkv + (size_t)b * SEQ * QKV_LD + (size_t)h * HD;
    const bf16_t* k_g = q_g + HID;
    const bf16_t* vt_g = Vt + (size_t)bh * HD * VT_LD;

    __shared__ __align__(16) bf16_t Vs[64][72];   // V^T tile [d][j]
    __shared__ float Op[4][32][64];               // jh=1 PV partials (32 KB)
    __shared__ float lsumS[8][32];                // per-wave row-sum partials

    const float QS = 0.125f * 1.44269504088896f;  // 1/sqrt(64) * log2(e)
    int i0 = tile * 128;

    // Q fragments (B-operand): Q[i = i0+ih*32+l32][k = ks*16 + hi*8 + e]
    bf16x8 qa[4];
    {
        const bf16_t* qrow = q_g + (size_t)(i0 + ih * 32 + l32) * QKV_LD + hi * 8;
#pragma unroll
        for (int ks = 0; ks < 4; ks++) {
            bf16x8 t = *(const bf16x8*)(qrow + ks * 16);
#pragma unroll
            for (int e = 0; e < 8; e++) qa[ks][e] = (bf16_t)((float)t[e] * QS);
        }
    }

    f32x16 o2[2] = {};   // O partial [i-block ih][d = dt*32+l32], own j-half
    float lsum = 0.0f;

    int sr = tid >> 3, sc = (tid & 7) * 8;  // V staging: 64 rows, 1 b128/thr

    // wave-private K row base (row j0 + jh*32 + l32, cols hi*8 + ks*16)
    const bf16_t* krow_base =
        k_g + (size_t)(jh * 32 + l32) * QKV_LD + hi * 8;

    // preload first V tile into registers
    bf16x8 vr = *(const bf16x8*)(vt_g + (size_t)sr * VT_LD + i0 + sc);

    for (int j0 = i0; j0 < SEQ; j0 += 64) {
        // --- K fragments direct from global (L2-hot); latency hidden by
        //     the two staging barriers below ---
        const bf16_t* krow = krow_base + (size_t)j0 * QKV_LD;
        bf16x8 ka0 = *(const bf16x8*)(krow);
        bf16x8 ka1 = *(const bf16x8*)(krow + 16);
        bf16x8 ka2 = *(const bf16x8*)(krow + 32);
        bf16x8 ka3 = *(const bf16x8*)(krow + 48);

        __syncthreads();  // prev iteration's Vs readers done
        *(bf16x8*)(&Vs[sr][sc]) = vr;
        __syncthreads();

        // issue next tile's V load; lands during compute
        if (j0 + 64 < SEQ) {
            vr = *(const bf16x8*)(vt_g + (size_t)sr * VT_LD + j0 + 64 + sc);
        }

        // --- QK: S^T quarter [32 j][32 i], 4 chained k-steps ---
        f32x16 st = {};
        st = MFMA32(ka0, qa[0], st);
        st = MFMA32(ka1, qa[1], st);
        st = MFMA32(ka2, qa[2], st);
        st = MFMA32(ka3, qa[3], st);

        // --- P = exp2(st), mask (first two j-blocks carry the diagonal) ---
        bf16x4 pk[4];  // pk[rq][r] = P[i=l32][j32 = 8rq+4hi+r], bf16
        if (j0 < i0 + 128) {
            int gi = i0 + ih * 32 + l32;
#pragma unroll
            for (int rq = 0; rq < 4; rq++) {
#pragma unroll
                for (int r = 0; r < 4; r++) {
                    int gj = j0 + jh * 32 + 8 * rq + 4 * hi + r;
                    float p = (gj >= gi) ? __builtin_amdgcn_exp2f(st[rq * 4 + r]) : 0.0f;
                    lsum += p;
                    pk[rq][r] = (bf16_t)p;
                }
            }
        } else {
#pragma unroll
            for (int rq = 0; rq < 4; rq++) {
#pragma unroll
                for (int r = 0; r < 4; r++) {
                    float p = __builtin_amdgcn_exp2f(st[rq * 4 + r]);
                    lsum += p;
                    pk[rq][r] = (bf16_t)p;
                }
            }
        }

        // --- PV: own j-half (32 j) x all 64 d; P fragments in-register ---
        // STATIC pk indexing only (rule #20); hi-select via v_cndmask.
#pragma unroll
        for (int ks2 = 0; ks2 < 2; ks2++) {
            uint2 pe = __builtin_bit_cast(uint2, pk[2 * ks2]);      // hi=0 slot
            uint2 po = __builtin_bit_cast(uint2, pk[2 * ks2 + 1]);  // hi=1 slot
            uint2 own, snd;
            own.x = hi ? po.x : pe.x;  own.y = hi ? po.y : pe.y;
            snd.x = hi ? pe.x : po.x;  snd.y = hi ? pe.y : po.y;
            uint2 rcv;
            rcv.x = (unsigned)__shfl_xor((int)snd.x, 32, 64);
            rcv.y = (unsigned)__shfl_xor((int)snd.y, 32, 64);
            uint4 fr;
            fr.x = hi ? rcv.x : own.x;
            fr.y = hi ? rcv.y : own.y;
            fr.z = hi ? own.x : rcv.x;
            fr.w = hi ? own.y : rcv.y;
            bf16x8 pa = __builtin_bit_cast(bf16x8, fr);
            // A[m=i(l32)][k = ks2*16 + hi*8 + e]
#pragma unroll
            for (int dt = 0; dt < 2; dt++) {
                bf16x8 vb = *(const bf16x8*)(
                    &Vs[dt * 32 + l32][jh * 32 + ks2 * 16 + hi * 8]);
                o2[dt] = MFMA32(pa, vb, o2[dt]);
            }
        }
    }

    // --- epilogue: row sums + jh-partial combine ---
    lsum += __shfl_xor(lsum, 32, 64);
    lsumS[wave][l32] = lsum;  // lanes l and l+32 write same value
    if (jh == 1) {
#pragma unroll
        for (int dt = 0; dt < 2; dt++)
#pragma unroll
            for (int rq = 0; rq < 4; rq++)
#pragma unroll
                for (int r = 0; r < 4; r++)
                    Op[ih][8 * rq + 4 * hi + r][dt * 32 + l32] = o2[dt][rq * 4 + r];
    }
    __syncthreads();

    if (jh == 0) {
#pragma unroll
        for (int rq = 0; rq < 4; rq++) {
#pragma unroll
            for (int r = 0; r < 4; r++) {
                int il = 8 * rq + 4 * hi + r;                 // local i
                float rs = lsumS[ih * 2][il] + lsumS[ih * 2 + 1][il];
                int gi = i0 + ih * 32 + il;
#pragma unroll
                for (int dt = 0; dt < 2; dt++) {
                    float val = o2[dt][rq * 4 + r] + Op[ih][il][dt * 32 + l32];
                    attn_out[(size_t)(b * SEQ + gi) * HID + h * HD + dt * 32 + l32] =
                        (bf16_t)(val / rs);
                }
            }
        }
    }
}

// ---------------------------------------------------------------------------
extern "C" void kernel_launch(void* const* d_in, const int* in_sizes, int n_in,
                              void* d_out, int out_size, void* d_ws, size_t ws_size,
                              hipStream_t stream) {
    const float* x     = (const float*)d_in[0];
    const float* w_qkv = (const float*)d_in[1];
    const float* b_qkv = (const float*)d_in[2];
    const float* w_out = (const float*)d_in[3];
    const float* b_out = (const float*)d_in[4];
    float* out = (float*)d_out;

    char* ws = (char*)d_ws;
    bf16_t* xbf   = (bf16_t*)(ws);               // 8.39 MB; dead after QKV GEMM
    bf16_t* wqkvT = (bf16_t*)(ws + 8388608);     // 6.29 MB
    bf16_t* woutT = (bf16_t*)(ws + 14680064);    // 2.10 MB
    bf16_t* qkv   = (bf16_t*)(ws + 16777216);    // 25.17 MB (V third unused)
    bf16_t* attn  = (bf16_t*)(ws + 41943040);    // 8.39 MB
    bf16_t* Vt    = (bf16_t*)(ws + 50331648);    // 8.52 MB; written by QKV GEMM

    prep_kernel<<<8192, 256, 0, stream>>>(x, w_qkv, w_out, xbf, wqkvT, woutT);

    // 256^2 deep-staged QKV GEMM (V fused-transposed into Vt): grid 192
    gemm_qkv_8ph<<<192, 512, 0, stream>>>(xbf, wqkvT, b_qkv, qkv, Vt,
                                          4096, 3072, 1024);

    attn_kernel<<<dim3(2 * NHEAD, SEQ / 128), 512, 0, stream>>>(qkv, Vt, attn);

    gemm_bt_bias<float, 128><<<dim3(1024 / 128, 4096 / 128), 256, 0, stream>>>(
        attn, woutT, b_out, out, 4096, 1024, 1024);
}

// Round 9
// 182.053 us; speedup vs baseline: 1.1012x; 1.1012x over previous
//
#include <hip/hip_runtime.h>
#include <hip/hip_bf16.h>
#include <stdint.h>
#include <stddef.h>

typedef __bf16 bf16_t;
typedef __bf16 bf16x4 __attribute__((ext_vector_type(4)));
typedef __bf16 bf16x8 __attribute__((ext_vector_type(8)));
typedef float f32x4 __attribute__((ext_vector_type(4)));
typedef float f32x16 __attribute__((ext_vector_type(16)));

#define MFMA16(a, b, c) __builtin_amdgcn_mfma_f32_16x16x32_bf16(a, b, c, 0, 0, 0)
#define MFMA32(a, b, c) __builtin_amdgcn_mfma_f32_32x32x16_bf16(a, b, c, 0, 0, 0)

// async global->LDS, 16 B per lane; LDS dest = uniform base + lane*16
#define GLL16(g, l)                                                      \
    __builtin_amdgcn_global_load_lds(                                    \
        (const __attribute__((address_space(1))) void*)(g),              \
        (__attribute__((address_space(3))) void*)(l), 16, 0, 0)

#define SEQ 2048
#define NHEAD 16
#define HD 64
#define HID 1024
#define QKV_LD 3072
#define VT_LD 2080  // 2048 + 32 pad: breaks 4 KB power-of-2 L2 set aliasing

// ---------------------------------------------------------------------------
// Fused prep: cast x -> bf16 (blocks 0..4095), transpose+cast w_qkv
// (4096..7167), transpose+cast w_out (7168..8191).
// ---------------------------------------------------------------------------
__global__ __launch_bounds__(256)
void prep_kernel(const float* __restrict__ x, const float* __restrict__ w_qkv,
                 const float* __restrict__ w_out, bf16_t* __restrict__ xbf,
                 bf16_t* __restrict__ wqkvT, bf16_t* __restrict__ woutT) {
    int L = blockIdx.x;
    int tid = threadIdx.x;
    if (L < 4096) {  // cast x
        int i = (L * 256 + tid) * 4;
        float4 v = *(const float4*)(x + i);
        bf16x4 o = {(bf16_t)v.x, (bf16_t)v.y, (bf16_t)v.z, (bf16_t)v.w};
        *(bf16x4*)(xbf + i) = o;
        return;
    }
    __shared__ bf16_t tile[32][33];
    const float* W;
    bf16_t* Wt;
    int N, bx, by;
    if (L < 7168) {
        int r = L - 4096;
        W = w_qkv; Wt = wqkvT; N = 3072; bx = r % 96; by = r / 96;
    } else {
        int r = L - 7168;
        W = w_out; Wt = woutT; N = 1024; bx = r % 32; by = r / 32;
    }
    int K = 1024;
    int n0 = bx * 32, k0 = by * 32;
    int tx = tid & 31, ty = tid >> 5;  // 32 x 8
#pragma unroll
    for (int i = 0; i < 4; i++)
        tile[ty + i * 8][tx] = (bf16_t)W[(size_t)(k0 + ty + i * 8) * N + n0 + tx];
    __syncthreads();
#pragma unroll
    for (int i = 0; i < 4; i++)
        Wt[(size_t)(n0 + ty + i * 8) * K + k0 + tx] = tile[tx][ty + i * 8];
}

// ---------------------------------------------------------------------------
// QKV GEMM, 256x256 tile, BK=64, 8-phase + deep staging.  FROZEN (control):
// five variants all measured 42.5-44.2 us / MfmaUtil 20-23%.  Diagnosis:
// LDS-read-issue bound (192 wave b128 reads/tile ~2300 cyc vs 620 cyc MFMA
// -> ~27% ceiling; matches measurement).  Frozen.
// ---------------------------------------------------------------------------
#define STAGE8(GB, LB, KOFF)                                                   \
    do {                                                                       \
        GLL16((GB) + (size_t)srow * K + (KOFF) + ssw,                          \
              (LB) + srow * 64 + (scl << 3));                                  \
        GLL16((GB) + (size_t)(srow + 64) * K + (KOFF) + ssw,                   \
              (LB) + (srow + 64) * 64 + (scl << 3));                           \
    } while (0)

// stage a full 256x64 A-tile + 256x64 B-tile (8 GLL16/wave) into buffer BUF
#define STAGE_ALL(ASB, BSB, KOFF)                                              \
    do {                                                                       \
        STAGE8(Bb, (BSB), KOFF);                                               \
        STAGE8(Ab, (ASB), KOFF);                                               \
        STAGE8(Bb + (size_t)128 * K, (BSB) + 128 * 64, KOFF);                  \
        STAGE8(Ab + (size_t)128 * K, (ASB) + 128 * 64, KOFF);                  \
    } while (0)

__global__ __launch_bounds__(512, 2)
void gemm_qkv_8ph(const bf16_t* __restrict__ A, const bf16_t* __restrict__ Bt,
                  const float* __restrict__ bias, bf16_t* __restrict__ C,
                  bf16_t* __restrict__ Vt, int M, int N, int K) {
    __shared__ __align__(16) bf16_t As[2][256][64];
    __shared__ __align__(16) bf16_t Bs[2][256][64];

    // T1: bijective XCD swizzle (gridDim.x % 8 == 0)
    int nbx = N >> 8;
    int bid = blockIdx.x;
    int swz = (bid & 7) * (gridDim.x >> 3) + (bid >> 3);
    int m0 = (swz / nbx) << 8;
    int n0 = (swz % nbx) << 8;

    int tid = threadIdx.x;
    int lane = tid & 63;
    int wave = tid >> 6;
    int l16 = lane & 15, quad = lane >> 4;
    int wm = (wave >> 2) << 7;  // 0 / 128
    int wn = (wave & 3) << 6;   // 0 / 64 / 128 / 192

    // staging coords: 512 thr x 16 B = one 64-row sweep; 8 chunks/row
    int srow = tid >> 3;  // 0..63
    int scl = tid & 7;
    int ssw = ((scl ^ (srow & 7)) << 3);  // pre-swizzled global chunk offset

    const bf16_t* Ab = A + (size_t)m0 * K;
    const bf16_t* Bb = Bt + (size_t)n0 * K;

    f32x4 acc[8][4] = {};  // [msub*4+mt][nsub*2+nt]
    bf16x8 a[4][2], b0[2][2], b1[2][2];

    const int NT = K >> 6;  // 16 K-tiles of 64

    // ---- prologue: burst-stage tile0 -> buf0, tile1 -> buf1; drain t0 ----
    STAGE_ALL(&As[0][0][0], &Bs[0][0][0], 0);
    STAGE_ALL(&As[1][0][0], &Bs[1][0][0], 64);
    asm volatile("s_waitcnt vmcnt(8)" ::: "memory");
    __builtin_amdgcn_s_barrier();

    for (int t = 0; t < NT; t++) {
        int buf = t & 1;
        const bf16_t* Asb = &As[buf][0][0];
        const bf16_t* Bsb = &Bs[buf][0][0];
        int k2 = (t + 2) << 6;

        // ===== phase 1: read A0 (msub0) + B0 (nsub0); P0 MFMA =====
#pragma unroll
        for (int mt = 0; mt < 4; mt++) {
            int row = wm + mt * 16 + l16;
#pragma unroll
            for (int ks = 0; ks < 2; ks++)
                a[mt][ks] = *(const bf16x8*)(
                    Asb + row * 64 + (((ks * 4 + quad) ^ (row & 7)) << 3));
        }
#pragma unroll
        for (int nt = 0; nt < 2; nt++) {
            int row = wn + nt * 16 + l16;
#pragma unroll
            for (int ks = 0; ks < 2; ks++)
                b0[nt][ks] = *(const bf16x8*)(
                    Bsb + row * 64 + (((ks * 4 + quad) ^ (row & 7)) << 3));
        }
        __builtin_amdgcn_s_barrier();
        asm volatile("s_waitcnt lgkmcnt(0)" ::: "memory");
        __builtin_amdgcn_s_setprio(1);
#pragma unroll
        for (int mt = 0; mt < 4; mt++)
#pragma unroll
            for (int nt = 0; nt < 2; nt++)
#pragma unroll
                for (int ks = 0; ks < 2; ks++)
                    acc[mt][nt] = MFMA16(a[mt][ks], b0[nt][ks], acc[mt][nt]);
        __builtin_amdgcn_s_setprio(0);
        __builtin_amdgcn_s_barrier();

        // ===== phase 2: read B1 (nsub1); P1 MFMA =====
#pragma unroll
        for (int nt = 0; nt < 2; nt++) {
            int row = wn + 32 + nt * 16 + l16;
#pragma unroll
            for (int ks = 0; ks < 2; ks++)
                b1[nt][ks] = *(const bf16x8*)(
                    Bsb + row * 64 + (((ks * 4 + quad) ^ (row & 7)) << 3));
        }
        __builtin_amdgcn_s_barrier();
        asm volatile("s_waitcnt lgkmcnt(0)" ::: "memory");
        __builtin_amdgcn_s_setprio(1);
#pragma unroll
        for (int mt = 0; mt < 4; mt++)
#pragma unroll
            for (int nt = 0; nt < 2; nt++)
#pragma unroll
                for (int ks = 0; ks < 2; ks++)
                    acc[mt][2 + nt] =
                        MFMA16(a[mt][ks], b1[nt][ks], acc[mt][2 + nt]);
        __builtin_amdgcn_s_setprio(0);
        __builtin_amdgcn_s_barrier();

        // ===== phase 3: read A1 (msub1); P2 MFMA =====
#pragma unroll
        for (int mt = 0; mt < 4; mt++) {
            int row = wm + 64 + mt * 16 + l16;
#pragma unroll
            for (int ks = 0; ks < 2; ks++)
                a[mt][ks] = *(const bf16x8*)(
                    Asb + row * 64 + (((ks * 4 + quad) ^ (row & 7)) << 3));
        }
        __builtin_amdgcn_s_barrier();
        asm volatile("s_waitcnt lgkmcnt(0)" ::: "memory");
        __builtin_amdgcn_s_setprio(1);
#pragma unroll
        for (int mt = 0; mt < 4; mt++)
#pragma unroll
            for (int nt = 0; nt < 2; nt++)
#pragma unroll
                for (int ks = 0; ks < 2; ks++)
                    acc[4 + mt][nt] =
                        MFMA16(a[mt][ks], b0[nt][ks], acc[4 + mt][nt]);
        __builtin_amdgcn_s_setprio(0);
        __builtin_amdgcn_s_barrier();

        // ===== phase 4: burst-stage t+2 -> current buf; counted drain; P3 ===
        if (t + 2 < NT) {
            STAGE_ALL(&As[buf][0][0], &Bs[buf][0][0], k2);
            // completes exactly tile t+1's 8 loads (issued 4 phases ago)
            asm volatile("s_waitcnt vmcnt(8)" ::: "memory");
        } else if (t + 1 < NT) {
            asm volatile("s_waitcnt vmcnt(0)" ::: "memory");
        }
        __builtin_amdgcn_s_setprio(1);
#pragma unroll
        for (int mt = 0; mt < 4; mt++)
#pragma unroll
            for (int nt = 0; nt < 2; nt++)
#pragma unroll
                for (int ks = 0; ks < 2; ks++)
                    acc[4 + mt][2 + nt] =
                        MFMA16(a[mt][ks], b1[nt][ks], acc[4 + mt][2 + nt]);
        __builtin_amdgcn_s_setprio(0);
        __builtin_amdgcn_s_barrier();
    }

    // ---- epilogue.  C/D: col=l16, row=quad*4+reg ----
    if (n0 < 2048) {
        // Q/K tiles: normal qkv store
#pragma unroll
        for (int mi = 0; mi < 8; mi++) {
            int row = m0 + wm + (mi >> 2) * 64 + (mi & 3) * 16 + quad * 4;
#pragma unroll
            for (int ni = 0; ni < 4; ni++) {
                int col = n0 + wn + (ni >> 1) * 32 + (ni & 1) * 16 + l16;
                float bv = bias[col];
#pragma unroll
                for (int r = 0; r < 4; r++)
                    C[(size_t)(row + r) * N + col] = (bf16_t)(acc[mi][ni][r] + bv);
            }
        }
    } else {
        // V tiles: transposed store into Vt[bh][d][s] (qkv V region unused)
#pragma unroll
        for (int mi = 0; mi < 8; mi++) {
            int row = m0 + wm + (mi >> 2) * 64 + (mi & 3) * 16 + quad * 4;
            int b = row >> 11, s = row & 2047;
#pragma unroll
            for (int ni = 0; ni < 4; ni++) {
                int col = n0 + wn + (ni >> 1) * 32 + (ni & 1) * 16 + l16;
                float bv = bias[col];
                int cv = col - 2048;
                int bh = b * 16 + (cv >> 6);
                bf16x4 pk;
#pragma unroll
                for (int r = 0; r < 4; r++)
                    pk[r] = (bf16_t)(acc[mi][ni][r] + bv);
                *(bf16x4*)(Vt + ((size_t)bh * HD + (cv & 63)) * VT_LD + s) = pk;
            }
        }
    }
}

// ---------------------------------------------------------------------------
// GEMM: C[M][N] = A[M][K] @ Bt[N][K]^T + bias[N].  bf16, fp32 accum, OutT out.
// 128xTN tile, BK=32, 256 thr, GLL width-16 staging into unpadded LDS.
// Out-projection TN=128: grid (8,32)=256 blocks (100% CU).
// ---------------------------------------------------------------------------
template <typename OutT, int TN>
__global__ __launch_bounds__(256)
void gemm_bt_bias(const bf16_t* __restrict__ A, const bf16_t* __restrict__ Bt,
                  const float* __restrict__ bias, OutT* __restrict__ C,
                  int M, int N, int K) {
    constexpr int NT = TN / 32;  // acc n-tiles per wave
    __shared__ __align__(16) bf16_t As[128][32];
    __shared__ __align__(16) bf16_t Bs[TN][32];

    int m0 = blockIdx.y * 128;
    int n0 = blockIdx.x * TN;
    int tid = threadIdx.x;
    int wave = tid >> 6, lane = tid & 63;
    int quad = lane >> 4, l16 = lane & 15;
    int wm = (wave >> 1) * 64, wn = (wave & 1) * (TN / 2);

    f32x4 acc[4][NT] = {};

    const bf16_t* a_base =
        A + (size_t)(m0 + wave * 32 + (lane >> 2)) * K + (lane & 3) * 8;
    const bf16_t* b_base =
        Bt + (size_t)(n0 + wave * (TN / 4) + (lane >> 2)) * K + (lane & 3) * 8;
    bf16_t* as_base = &As[wave * 32][0];
    bf16_t* bs_base = &Bs[wave * (TN / 4)][0];

    for (int k0 = 0; k0 < K; k0 += 32) {
        GLL16(a_base + k0, as_base);
        GLL16(a_base + 16 * K + k0, as_base + 16 * 32);
        GLL16(b_base + k0, bs_base);
        if (TN == 128) GLL16(b_base + 16 * K + k0, bs_base + 16 * 32);
        __syncthreads();

        bf16x8 af[4], bfr[NT];
#pragma unroll
        for (int t = 0; t < 4; t++)
            af[t] = *(const bf16x8*)(&As[wm + t * 16 + l16][quad * 8]);
#pragma unroll
        for (int t = 0; t < NT; t++)
            bfr[t] = *(const bf16x8*)(&Bs[wn + t * 16 + l16][quad * 8]);
#pragma unroll
        for (int mt = 0; mt < 4; mt++)
#pragma unroll
            for (int nt = 0; nt < NT; nt++)
                acc[mt][nt] = MFMA16(af[mt], bfr[nt], acc[mt][nt]);
        __syncthreads();
    }

#pragma unroll
    for (int mt = 0; mt < 4; mt++) {
        int row = m0 + wm + mt * 16 + quad * 4;
#pragma unroll
        for (int nt = 0; nt < NT; nt++) {
            int col = n0 + wn + nt * 16 + l16;
            float bv = bias[col];
#pragma unroll
            for (int r = 0; r < 4; r++)
                C[(size_t)(row + r) * N + col] = (OutT)(acc[mt][nt][r] + bv);
        }
    }
}

// ---------------------------------------------------------------------------
// Attention, mask j >= i, mfma_f32_32x32x16_bf16.  TI=128, BJ=64, 8 waves
// (ih=w>>1 = i 32-block, jh=w&1 = j half).  P in registers (R7).
//
// ROUND-9: (a) REVERT R8's K-direct-from-global -- the ka pattern (32 rows
// 6 KB apart, 32 B/row) fragmented each wave load into ~32 transactions and
// cost +11 us (54.5 vs <=43).  K returns to coalesced LDS staging.
// (b) DOUBLE-BUFFERED Ks/Vs -> ONE barrier per iteration (was 2).  R8's
// counters (MfmaUtil 12 / VALU 22 / Occ 27) show this family is ~66% idle =
// serialization-bound; the sync->write->sync staging wall was the last
// 2-barrier structure.  Safety: writes to buf^1 in iter j are separated
// from iter j-1's reads of buf^1 by the barrier ending j-1 (__syncthreads
// drains lgkm, so reads are in regs before any wave passes); reads in j+1
// are separated from j's writes by the barrier ending j.  K/V global
// prefetch distance becomes 2 tiles (more slack, off the critical path).
// LDS: 2*(9.2+9.2) KB + Op 32 KB + 1 KB = 70 KB -> 2 blocks/CU (grid 512
// can't use more anyway).
// Fragment mapping: A/B[m|n = lane&31][k = (lane>>5)*8 + e];
// C/D: col = lane&31, row = (reg&3) + 8*(reg>>2) + 4*(lane>>5)  [m74/m101].
// ---------------------------------------------------------------------------
__global__ __launch_bounds__(512, 4)
void attn_kernel(const bf16_t* __restrict__ qkv, const bf16_t* __restrict__ Vt,
                 bf16_t* __restrict__ attn_out) {
    int bh = blockIdx.x;        // linear%8 == bh%8 -> XCD pin
    int tile = (blockIdx.y < 8) ? blockIdx.y : (23 - blockIdx.y);
    int b = bh >> 4, h = bh & 15;

    int tid = threadIdx.x, wave = tid >> 6, lane = tid & 63;
    int l32 = lane & 31, hi = lane >> 5;
    int ih = wave >> 1, jh = wave & 1;

    const bf16_t* q_g = qkv + (size_t)b * SEQ * QKV_LD + (size_t)h * HD;
    const bf16_t* k_g = q_g + HID;
    const bf16_t* vt_g = Vt + (size_t)bh * HD * VT_LD;

    __shared__ __align__(16) bf16_t Ks[2][64][72];  // K tile [j][d], dbuf
    __shared__ __align__(16) bf16_t Vs[2][64][72];  // V^T tile [d][j], dbuf
    __shared__ float Op[4][32][64];                 // jh=1 PV partials (32 KB)
    __shared__ float lsumS[8][32];                  // per-wave row-sum partials

    const float QS = 0.125f * 1.44269504088896f;  // 1/sqrt(64) * log2(e)
    int i0 = tile * 128;

    // Q fragments (B-operand): Q[i = i0+ih*32+l32][k = ks*16 + hi*8 + e]
    bf16x8 qa[4];
    {
        const bf16_t* qrow = q_g + (size_t)(i0 + ih * 32 + l32) * QKV_LD + hi * 8;
#pragma unroll
        for (int ks = 0; ks < 4; ks++) {
            bf16x8 t = *(const bf16x8*)(qrow + ks * 16);
#pragma unroll
            for (int e = 0; e < 8; e++) qa[ks][e] = (bf16_t)((float)t[e] * QS);
        }
    }

    f32x16 o2[2] = {};   // O partial [i-block ih][d = dt*32+l32], own j-half
    float lsum = 0.0f;

    int sr = tid >> 3, sc = (tid & 7) * 8;  // staging: 64 rows, 1 b128/thread
    const bf16_t* kst = k_g + (size_t)sr * QKV_LD + sc;   // K stage base
    const bf16_t* vst = vt_g + (size_t)sr * VT_LD + sc;   // V stage base

    // prologue: tile i0 -> buf 0; prefetch tile i0+64 into regs
    bf16x8 kr = *(const bf16x8*)(kst + (size_t)i0 * QKV_LD);
    bf16x8 vr = *(const bf16x8*)(vst + i0);
    *(bf16x8*)(&Ks[0][sr][sc]) = kr;
    *(bf16x8*)(&Vs[0][sr][sc]) = vr;
    if (i0 + 64 < SEQ) {
        kr = *(const bf16x8*)(kst + (size_t)(i0 + 64) * QKV_LD);
        vr = *(const bf16x8*)(vst + i0 + 64);
    }
    __syncthreads();

    int cur = 0;
    for (int j0 = i0; j0 < SEQ; j0 += 64) {
        // --- QK: S^T quarter [32 j][32 i], 4 chained k-steps (Ks[cur]) ---
        f32x16 st = {};
#pragma unroll
        for (int ks = 0; ks < 4; ks++) {
            bf16x8 ka = *(const bf16x8*)(&Ks[cur][jh * 32 + l32][ks * 16 + hi * 8]);
            st = MFMA32(ka, qa[ks], st);
        }

        // --- stage tile j0+64 into buf cur^1 (its readers drained at the
        //     barrier ending the previous iteration); prefetch j0+128 ---
        if (j0 + 64 < SEQ) {
            *(bf16x8*)(&Ks[cur ^ 1][sr][sc]) = kr;
            *(bf16x8*)(&Vs[cur ^ 1][sr][sc]) = vr;
            if (j0 + 128 < SEQ) {
                kr = *(const bf16x8*)(kst + (size_t)(j0 + 128) * QKV_LD);
                vr = *(const bf16x8*)(vst + j0 + 128);
            }
        }

        // --- P = exp2(st), mask (first two j-blocks carry the diagonal) ---
        bf16x4 pk[4];  // pk[rq][r] = P[i=l32][j32 = 8rq+4hi+r], bf16
        if (j0 < i0 + 128) {
            int gi = i0 + ih * 32 + l32;
#pragma unroll
            for (int rq = 0; rq < 4; rq++) {
#pragma unroll
                for (int r = 0; r < 4; r++) {
                    int gj = j0 + jh * 32 + 8 * rq + 4 * hi + r;
                    float p = (gj >= gi) ? __builtin_amdgcn_exp2f(st[rq * 4 + r]) : 0.0f;
                    lsum += p;
                    pk[rq][r] = (bf16_t)p;
                }
            }
        } else {
#pragma unroll
            for (int rq = 0; rq < 4; rq++) {
#pragma unroll
                for (int r = 0; r < 4; r++) {
                    float p = __builtin_amdgcn_exp2f(st[rq * 4 + r]);
                    lsum += p;
                    pk[rq][r] = (bf16_t)p;
                }
            }
        }

        // --- PV: own j-half (32 j) x all 64 d; P fragments in-register ---
        // STATIC pk indexing only (rule #20); hi-select via v_cndmask.
#pragma unroll
        for (int ks2 = 0; ks2 < 2; ks2++) {
            uint2 pe = __builtin_bit_cast(uint2, pk[2 * ks2]);      // hi=0 slot
            uint2 po = __builtin_bit_cast(uint2, pk[2 * ks2 + 1]);  // hi=1 slot
            uint2 own, snd;
            own.x = hi ? po.x : pe.x;  own.y = hi ? po.y : pe.y;
            snd.x = hi ? pe.x : po.x;  snd.y = hi ? pe.y : po.y;
            uint2 rcv;
            rcv.x = (unsigned)__shfl_xor((int)snd.x, 32, 64);
            rcv.y = (unsigned)__shfl_xor((int)snd.y, 32, 64);
            uint4 fr;
            fr.x = hi ? rcv.x : own.x;
            fr.y = hi ? rcv.y : own.y;
            fr.z = hi ? own.x : rcv.x;
            fr.w = hi ? own.y : rcv.y;
            bf16x8 pa = __builtin_bit_cast(bf16x8, fr);
            // A[m=i(l32)][k = ks2*16 + hi*8 + e]
#pragma unroll
            for (int dt = 0; dt < 2; dt++) {
                bf16x8 vb = *(const bf16x8*)(
                    &Vs[cur][dt * 32 + l32][jh * 32 + ks2 * 16 + hi * 8]);
                o2[dt] = MFMA32(pa, vb, o2[dt]);
            }
        }

        __syncthreads();  // buf cur^1 staged; buf cur reads drained
        cur ^= 1;
    }

    // --- epilogue: row sums + jh-partial combine ---
    lsum += __shfl_xor(lsum, 32, 64);
    lsumS[wave][l32] = lsum;  // lanes l and l+32 write same value
    if (jh == 1) {
#pragma unroll
        for (int dt = 0; dt < 2; dt++)
#pragma unroll
            for (int rq = 0; rq < 4; rq++)
#pragma unroll
                for (int r = 0; r < 4; r++)
                    Op[ih][8 * rq + 4 * hi + r][dt * 32 + l32] = o2[dt][rq * 4 + r];
    }
    __syncthreads();

    if (jh == 0) {
#pragma unroll
        for (int rq = 0; rq < 4; rq++) {
#pragma unroll
            for (int r = 0; r < 4; r++) {
                int il = 8 * rq + 4 * hi + r;                 // local i
                float rs = lsumS[ih * 2][il] + lsumS[ih * 2 + 1][il];
                int gi = i0 + ih * 32 + il;
#pragma unroll
                for (int dt = 0; dt < 2; dt++) {
                    float val = o2[dt][rq * 4 + r] + Op[ih][il][dt * 32 + l32];
                    attn_out[(size_t)(b * SEQ + gi) * HID + h * HD + dt * 32 + l32] =
                        (bf16_t)(val / rs);
                }
            }
        }
    }
}

// ---------------------------------------------------------------------------
extern "C" void kernel_launch(void* const* d_in, const int* in_sizes, int n_in,
                              void* d_out, int out_size, void* d_ws, size_t ws_size,
                              hipStream_t stream) {
    const float* x     = (const float*)d_in[0];
    const float* w_qkv = (const float*)d_in[1];
    const float* b_qkv = (const float*)d_in[2];
    const float* w_out = (const float*)d_in[3];
    const float* b_out = (const float*)d_in[4];
    float* out = (float*)d_out;

    char* ws = (char*)d_ws;
    bf16_t* xbf   = (bf16_t*)(ws);               // 8.39 MB; dead after QKV GEMM
    bf16_t* wqkvT = (bf16_t*)(ws + 8388608);     // 6.29 MB
    bf16_t* woutT = (bf16_t*)(ws + 14680064);    // 2.10 MB
    bf16_t* qkv   = (bf16_t*)(ws + 16777216);    // 25.17 MB (V third unused)
    bf16_t* attn  = (bf16_t*)(ws + 41943040);    // 8.39 MB
    bf16_t* Vt    = (bf16_t*)(ws + 50331648);    // 8.52 MB; written by QKV GEMM

    prep_kernel<<<8192, 256, 0, stream>>>(x, w_qkv, w_out, xbf, wqkvT, woutT);

    // 256^2 deep-staged QKV GEMM (V fused-transposed into Vt): grid 192
    gemm_qkv_8ph<<<192, 512, 0, stream>>>(xbf, wqkvT, b_qkv, qkv, Vt,
                                          4096, 3072, 1024);

    attn_kernel<<<dim3(2 * NHEAD, SEQ / 128), 512, 0, stream>>>(qkv, Vt, attn);

    gemm_bt_bias<float, 128><<<dim3(1024 / 128, 4096 / 128), 256, 0, stream>>>(
        attn, woutT, b_out, out, 4096, 1024, 1024);
}

// Round 10
// 174.388 us; speedup vs baseline: 1.1496x; 1.0440x over previous
//
#include <hip/hip_runtime.h>
#include <hip/hip_bf16.h>
#include <stdint.h>
#include <stddef.h>

typedef __bf16 bf16_t;
typedef __bf16 bf16x4 __attribute__((ext_vector_type(4)));
typedef __bf16 bf16x8 __attribute__((ext_vector_type(8)));
typedef float f32x4 __attribute__((ext_vector_type(4)));
typedef float f32x16 __attribute__((ext_vector_type(16)));

#define MFMA16(a, b, c) __builtin_amdgcn_mfma_f32_16x16x32_bf16(a, b, c, 0, 0, 0)
#define MFMA32(a, b, c) __builtin_amdgcn_mfma_f32_32x32x16_bf16(a, b, c, 0, 0, 0)

// async global->LDS, 16 B per lane; LDS dest = uniform base + lane*16
#define GLL16(g, l)                                                      \
    __builtin_amdgcn_global_load_lds(                                    \
        (const __attribute__((address_space(1))) void*)(g),              \
        (__attribute__((address_space(3))) void*)(l), 16, 0, 0)

#define SEQ 2048
#define NHEAD 16
#define HD 64
#define HID 1024
#define QKV_LD 3072
#define VT_LD 2080  // 2048 + 32 pad: breaks 4 KB power-of-2 L2 set aliasing

// ---------------------------------------------------------------------------
// SESSION-FINAL: exact revert to the round-2-measured configuration
// (172.8 us, best of 9 measurements).  Meta-analysis: all post-R2 deltas
// (1-barrier QKV 178.3, deep-staged QKV 178.3, in-reg-P attn + TN=128
// 179.9, dbuf attn 182.1) were neutral-to-negative; the two real wins
// (Vt-fusion into the QKV epilogue, TI=128 attn) are in this kernel.
// ---------------------------------------------------------------------------

// ---------------------------------------------------------------------------
// Fused prep: cast x -> bf16 (blocks 0..4095), transpose+cast w_qkv
// (4096..7167), transpose+cast w_out (7168..8191).
// ---------------------------------------------------------------------------
__global__ __launch_bounds__(256)
void prep_kernel(const float* __restrict__ x, const float* __restrict__ w_qkv,
                 const float* __restrict__ w_out, bf16_t* __restrict__ xbf,
                 bf16_t* __restrict__ wqkvT, bf16_t* __restrict__ woutT) {
    int L = blockIdx.x;
    int tid = threadIdx.x;
    if (L < 4096) {  // cast x
        int i = (L * 256 + tid) * 4;
        float4 v = *(const float4*)(x + i);
        bf16x4 o = {(bf16_t)v.x, (bf16_t)v.y, (bf16_t)v.z, (bf16_t)v.w};
        *(bf16x4*)(xbf + i) = o;
        return;
    }
    __shared__ bf16_t tile[32][33];
    const float* W;
    bf16_t* Wt;
    int N, bx, by;
    if (L < 7168) {
        int r = L - 4096;
        W = w_qkv; Wt = wqkvT; N = 3072; bx = r % 96; by = r / 96;
    } else {
        int r = L - 7168;
        W = w_out; Wt = woutT; N = 1024; bx = r % 32; by = r / 32;
    }
    int K = 1024;
    int n0 = bx * 32, k0 = by * 32;
    int tx = tid & 31, ty = tid >> 5;  // 32 x 8
#pragma unroll
    for (int i = 0; i < 4; i++)
        tile[ty + i * 8][tx] = (bf16_t)W[(size_t)(k0 + ty + i * 8) * N + n0 + tx];
    __syncthreads();
#pragma unroll
    for (int i = 0; i < 4; i++)
        Wt[(size_t)(n0 + ty + i * 8) * K + k0 + tx] = tile[tx][ty + i * 8];
}

// ---------------------------------------------------------------------------
// QKV GEMM, 256x256 tile, BK=64, 8-phase schedule (T1+T2+T3+T4+T5).
// C[M][N] = A[M][K] @ Bt[N][K]^T + bias[N], bf16 out.
//
// V-tile workgroups (n0 >= 2048) skip the qkv store and instead write the
// transposed Vt[bh][d][s] directly from the accumulator (bit-identical to a
// separate transpose pass; kills that kernel + 17 MB of HBM traffic).
//
// 512 thr = 8 waves (2M x 4N); per-wave output 128x64; 16 MFMA_16x16x32 per
// phase.  LDS 128 KiB: [2 dbuf][256][64] A and B.  LDS chunk swizzle (T2):
// stored chunk c holds global chunk c ^ (row&7); GLL16 dest linear, global
// source pre-swizzled, same XOR on ds_read_b128.
//
// Staging: ph1 (t+1)B-h1 -> other buf; ph2 (t+1)A-h1 -> other buf;
// ph3 (t+2)B-h0 -> current buf (B fully read after ph2); ph4 (t+2)A-h0 ->
// current buf (A fully read after ph3).  Single vmcnt(4) drain per K-tile.
// ---------------------------------------------------------------------------
#define STAGE8(GB, LB, KOFF)                                                   \
    do {                                                                       \
        GLL16((GB) + (size_t)srow * K + (KOFF) + ssw,                          \
              (LB) + srow * 64 + (scl << 3));                                  \
        GLL16((GB) + (size_t)(srow + 64) * K + (KOFF) + ssw,                   \
              (LB) + (srow + 64) * 64 + (scl << 3));                           \
    } while (0)

__global__ __launch_bounds__(512, 2)
void gemm_qkv_8ph(const bf16_t* __restrict__ A, const bf16_t* __restrict__ Bt,
                  const float* __restrict__ bias, bf16_t* __restrict__ C,
                  bf16_t* __restrict__ Vt, int M, int N, int K) {
    __shared__ __align__(16) bf16_t As[2][256][64];
    __shared__ __align__(16) bf16_t Bs[2][256][64];

    // T1: bijective XCD swizzle (gridDim.x % 8 == 0)
    int nbx = N >> 8;
    int bid = blockIdx.x;
    int swz = (bid & 7) * (gridDim.x >> 3) + (bid >> 3);
    int m0 = (swz / nbx) << 8;
    int n0 = (swz % nbx) << 8;

    int tid = threadIdx.x;
    int lane = tid & 63;
    int wave = tid >> 6;
    int l16 = lane & 15, quad = lane >> 4;
    int wm = (wave >> 2) << 7;  // 0 / 128
    int wn = (wave & 3) << 6;   // 0 / 64 / 128 / 192

    // staging coords: 512 thr x 16 B = one 64-row sweep; 8 chunks/row
    int srow = tid >> 3;  // 0..63
    int scl = tid & 7;
    int ssw = ((scl ^ (srow & 7)) << 3);  // pre-swizzled global chunk offset

    const bf16_t* Ab = A + (size_t)m0 * K;
    const bf16_t* Bb = Bt + (size_t)n0 * K;

    f32x4 acc[8][4] = {};  // [msub*4+mt][nsub*2+nt]
    bf16x8 af[4][2], b0[2][2], b1[2][2];

    const int NT = K >> 6;  // 16 K-tiles of 64

    // ---- prologue: tile0 H1..H4, tile1 H1,H2; drain tile0 (vmcnt(4)) ----
    STAGE8(Bb, &Bs[0][0][0], 0);                        // t0 B-half0
    STAGE8(Ab, &As[0][0][0], 0);                        // t0 A-half0
    STAGE8(Bb + (size_t)128 * K, &Bs[0][128][0], 0);    // t0 B-half1
    STAGE8(Ab + (size_t)128 * K, &As[0][128][0], 0);    // t0 A-half1
    STAGE8(Bb, &Bs[1][0][0], 64);                       // t1 B-half0
    STAGE8(Ab, &As[1][0][0], 64);                       // t1 A-half0
    asm volatile("s_waitcnt vmcnt(4)" ::: "memory");
    __builtin_amdgcn_s_barrier();

    for (int t = 0; t < NT; t++) {
        int buf = t & 1;
        const bf16_t* Asb = &As[buf][0][0];
        const bf16_t* Bsb = &Bs[buf][0][0];
        int k1 = (t + 1) << 6;
        int k2 = (t + 2) << 6;

        // ===== phase 1: read A-msub0 + B-nsub0; stage (t+1) B-half1 =====
#pragma unroll
        for (int mt = 0; mt < 4; mt++) {
            int row = wm + mt * 16 + l16;
#pragma unroll
            for (int ks = 0; ks < 2; ks++)
                af[mt][ks] = *(const bf16x8*)(
                    Asb + row * 64 + (((ks * 4 + quad) ^ (row & 7)) << 3));
        }
#pragma unroll
        for (int nt = 0; nt < 2; nt++) {
            int row = wn + nt * 16 + l16;
#pragma unroll
            for (int ks = 0; ks < 2; ks++)
                b0[nt][ks] = *(const bf16x8*)(
                    Bsb + row * 64 + (((ks * 4 + quad) ^ (row & 7)) << 3));
        }
        if (t + 1 < NT) STAGE8(Bb + (size_t)128 * K, &Bs[buf ^ 1][128][0], k1);
        __builtin_amdgcn_s_barrier();
        asm volatile("s_waitcnt lgkmcnt(0)" ::: "memory");
        __builtin_amdgcn_s_setprio(1);
#pragma unroll
        for (int mt = 0; mt < 4; mt++)
#pragma unroll
            for (int nt = 0; nt < 2; nt++)
#pragma unroll
                for (int ks = 0; ks < 2; ks++)
                    acc[mt][nt] = MFMA16(af[mt][ks], b0[nt][ks], acc[mt][nt]);
        __builtin_amdgcn_s_setprio(0);
        __builtin_amdgcn_s_barrier();

        // ===== phase 2: read B-nsub1; stage (t+1) A-half1 =====
#pragma unroll
        for (int nt = 0; nt < 2; nt++) {
            int row = wn + 32 + nt * 16 + l16;
#pragma unroll
            for (int ks = 0; ks < 2; ks++)
                b1[nt][ks] = *(const bf16x8*)(
                    Bsb + row * 64 + (((ks * 4 + quad) ^ (row & 7)) << 3));
        }
        if (t + 1 < NT) STAGE8(Ab + (size_t)128 * K, &As[buf ^ 1][128][0], k1);
        __builtin_amdgcn_s_barrier();
        asm volatile("s_waitcnt lgkmcnt(0)" ::: "memory");
        __builtin_amdgcn_s_setprio(1);
#pragma unroll
        for (int mt = 0; mt < 4; mt++)
#pragma unroll
            for (int nt = 0; nt < 2; nt++)
#pragma unroll
                for (int ks = 0; ks < 2; ks++)
                    acc[mt][2 + nt] =
                        MFMA16(af[mt][ks], b1[nt][ks], acc[mt][2 + nt]);
        __builtin_amdgcn_s_setprio(0);
        __builtin_amdgcn_s_barrier();

        // ===== phase 3: read A-msub1; stage (t+2) B-half0 (current buf) =====
#pragma unroll
        for (int mt = 0; mt < 4; mt++) {
            int row = wm + 64 + mt * 16 + l16;
#pragma unroll
            for (int ks = 0; ks < 2; ks++)
                af[mt][ks] = *(const bf16x8*)(
                    Asb + row * 64 + (((ks * 4 + quad) ^ (row & 7)) << 3));
        }
        if (t + 2 < NT) STAGE8(Bb, &Bs[buf][0][0], k2);
        __builtin_amdgcn_s_barrier();
        asm volatile("s_waitcnt lgkmcnt(0)" ::: "memory");
        __builtin_amdgcn_s_setprio(1);
#pragma unroll
        for (int mt = 0; mt < 4; mt++)
#pragma unroll
            for (int nt = 0; nt < 2; nt++)
#pragma unroll
                for (int ks = 0; ks < 2; ks++)
                    acc[4 + mt][nt] =
                        MFMA16(af[mt][ks], b0[nt][ks], acc[4 + mt][nt]);
        __builtin_amdgcn_s_setprio(0);
        __builtin_amdgcn_s_barrier();

        // ===== phase 4: stage (t+2) A-half0 (current buf); counted drain ====
        if (t + 2 < NT) {
            STAGE8(Ab, &As[buf][0][0], k2);
            asm volatile("s_waitcnt vmcnt(4)" ::: "memory");
        } else if (t + 1 < NT) {
            asm volatile("s_waitcnt vmcnt(0)" ::: "memory");
        }
        __builtin_amdgcn_s_barrier();
        __builtin_amdgcn_s_setprio(1);
#pragma unroll
        for (int mt = 0; mt < 4; mt++)
#pragma unroll
            for (int nt = 0; nt < 2; nt++)
#pragma unroll
                for (int ks = 0; ks < 2; ks++)
                    acc[4 + mt][2 + nt] =
                        MFMA16(af[mt][ks], b1[nt][ks], acc[4 + mt][2 + nt]);
        __builtin_amdgcn_s_setprio(0);
        __builtin_amdgcn_s_barrier();
    }

    // ---- epilogue.  C/D: col=l16, row=quad*4+reg ----
    if (n0 < 2048) {
        // Q/K tiles: normal qkv store
#pragma unroll
        for (int mi = 0; mi < 8; mi++) {
            int row = m0 + wm + (mi >> 2) * 64 + (mi & 3) * 16 + quad * 4;
#pragma unroll
            for (int ni = 0; ni < 4; ni++) {
                int col = n0 + wn + (ni >> 1) * 32 + (ni & 1) * 16 + l16;
                float bv = bias[col];
#pragma unroll
                for (int r = 0; r < 4; r++)
                    C[(size_t)(row + r) * N + col] = (bf16_t)(acc[mi][ni][r] + bv);
            }
        }
    } else {
        // V tiles: transposed store into Vt[bh][d][s] (qkv V region unused)
#pragma unroll
        for (int mi = 0; mi < 8; mi++) {
            int row = m0 + wm + (mi >> 2) * 64 + (mi & 3) * 16 + quad * 4;
            int b = row >> 11, s = row & 2047;
#pragma unroll
            for (int ni = 0; ni < 4; ni++) {
                int col = n0 + wn + (ni >> 1) * 32 + (ni & 1) * 16 + l16;
                float bv = bias[col];
                int cv = col - 2048;
                int bh = b * 16 + (cv >> 6);
                bf16x4 pk;
#pragma unroll
                for (int r = 0; r < 4; r++)
                    pk[r] = (bf16_t)(acc[mi][ni][r] + bv);
                *(bf16x4*)(Vt + ((size_t)bh * HD + (cv & 63)) * VT_LD + s) = pk;
            }
        }
    }
}

// ---------------------------------------------------------------------------
// GEMM: C[M][N] = A[M][K] @ Bt[N][K]^T + bias[N].  bf16, fp32 accum, OutT out.
// 128xTN tile, BK=32, 256 thr, GLL width-16 staging into unpadded LDS.
// (out-projection: N=1024, TN=64 -> grid (16,32)=512 blocks, as measured
// in the best run)
// ---------------------------------------------------------------------------
template <typename OutT, int TN>
__global__ __launch_bounds__(256)
void gemm_bt_bias(const bf16_t* __restrict__ A, const bf16_t* __restrict__ Bt,
                  const float* __restrict__ bias, OutT* __restrict__ C,
                  int M, int N, int K) {
    constexpr int NT = TN / 32;  // acc n-tiles per wave
    __shared__ __align__(16) bf16_t As[128][32];
    __shared__ __align__(16) bf16_t Bs[TN][32];

    int m0 = blockIdx.y * 128;
    int n0 = blockIdx.x * TN;
    int tid = threadIdx.x;
    int wave = tid >> 6, lane = tid & 63;
    int quad = lane >> 4, l16 = lane & 15;
    int wm = (wave >> 1) * 64, wn = (wave & 1) * (TN / 2);

    f32x4 acc[4][NT] = {};

    const bf16_t* a_base =
        A + (size_t)(m0 + wave * 32 + (lane >> 2)) * K + (lane & 3) * 8;
    const bf16_t* b_base =
        Bt + (size_t)(n0 + wave * (TN / 4) + (lane >> 2)) * K + (lane & 3) * 8;
    bf16_t* as_base = &As[wave * 32][0];
    bf16_t* bs_base = &Bs[wave * (TN / 4)][0];

    for (int k0 = 0; k0 < K; k0 += 32) {
        GLL16(a_base + k0, as_base);
        GLL16(a_base + 16 * K + k0, as_base + 16 * 32);
        GLL16(b_base + k0, bs_base);
        if (TN == 128) GLL16(b_base + 16 * K + k0, bs_base + 16 * 32);
        __syncthreads();

        bf16x8 af[4], bfr[NT];
#pragma unroll
        for (int t = 0; t < 4; t++)
            af[t] = *(const bf16x8*)(&As[wm + t * 16 + l16][quad * 8]);
#pragma unroll
        for (int t = 0; t < NT; t++)
            bfr[t] = *(const bf16x8*)(&Bs[wn + t * 16 + l16][quad * 8]);
#pragma unroll
        for (int mt = 0; mt < 4; mt++)
#pragma unroll
            for (int nt = 0; nt < NT; nt++)
                acc[mt][nt] = MFMA16(af[mt], bfr[nt], acc[mt][nt]);
        __syncthreads();
    }

#pragma unroll
    for (int mt = 0; mt < 4; mt++) {
        int row = m0 + wm + mt * 16 + quad * 4;
#pragma unroll
        for (int nt = 0; nt < NT; nt++) {
            int col = n0 + wn + nt * 16 + l16;
            float bv = bias[col];
#pragma unroll
            for (int r = 0; r < 4; r++)
                C[(size_t)(row + r) * N + col] = (OutT)(acc[mt][nt][r] + bv);
        }
    }
}

// ---------------------------------------------------------------------------
// Attention, mask j >= i, mfma_f32_32x32x16_bf16.
// TI=128, BJ=64, 8 waves (ih=w>>1 = i 32-block, jh=w&1 = j/d half):
//   QK: S^T quarter = K[jh-half] . Q[ih-block]^T (A=K from LDS, B=Q regs).
//       C-layout: i = lane&31, j = r+8rq+4hi  [m74/m101].
//   PV: O quarter (ih, d-half jh) over all 64 j: A=Ps, B=Vs frags.
// One 64-row K/V tile serves 128 q-rows.  LDS 36.9 KB -> 2 blocks/CU.
// Mask covers the first TWO j-blocks (j0 < i0+128), per-element gj>=gi.
// Tile remap y<8?y:23-y pairs long+short tiles on co-resident wgs.
// Fragment mapping: A/B[m|n = lane&31][k = (lane>>5)*8 + e].
// ---------------------------------------------------------------------------
__global__ __launch_bounds__(512, 4)
void attn_kernel(const bf16_t* __restrict__ qkv, const bf16_t* __restrict__ Vt,
                 bf16_t* __restrict__ attn_out) {
    int bh = blockIdx.x;        // linear%8 == bh%8 -> XCD pin
    int tile = (blockIdx.y < 8) ? blockIdx.y : (23 - blockIdx.y);
    int b = bh >> 4, h = bh & 15;

    int tid = threadIdx.x, wave = tid >> 6, lane = tid & 63;
    int l32 = lane & 31, hi = lane >> 5;
    int ih = wave >> 1, jh = wave & 1;

    const bf16_t* q_g = qkv + (size_t)b * SEQ * QKV_LD + (size_t)h * HD;
    const bf16_t* k_g = q_g + HID;
    const bf16_t* vt_g = Vt + (size_t)bh * HD * VT_LD;

    __shared__ __align__(16) bf16_t Ks[64][72];   // K tile [j][d]
    __shared__ __align__(16) bf16_t Vs[64][72];   // V^T tile [d][j]
    __shared__ __align__(16) bf16_t Ps[128][68];  // P [i][j], block-shared
    __shared__ float lsumS[8][32];                // per-wave row-sum partials

    const float QS = 0.125f * 1.44269504088896f;  // 1/sqrt(64) * log2(e)
    int i0 = tile * 128;

    // Q fragments (B-operand): Q[i = i0+ih*32+l32][k = ks*16 + hi*8 + e]
    bf16x8 qa[4];
    {
        const bf16_t* qrow = q_g + (size_t)(i0 + ih * 32 + l32) * QKV_LD + hi * 8;
#pragma unroll
        for (int ks = 0; ks < 4; ks++) {
            bf16x8 t = *(const bf16x8*)(qrow + ks * 16);
#pragma unroll
            for (int e = 0; e < 8; e++) qa[ks][e] = (bf16_t)((float)t[e] * QS);
        }
    }

    f32x16 o = {};
    float lsum = 0.0f;

    int sr = tid >> 3, sc = (tid & 7) * 8;  // staging: 64 rows, 1 b128/thread

    // preload first K/V tile into registers
    bf16x8 kr = *(const bf16x8*)(k_g + (size_t)(i0 + sr) * QKV_LD + sc);
    bf16x8 vr = *(const bf16x8*)(vt_g + (size_t)sr * VT_LD + i0 + sc);

    for (int j0 = i0; j0 < SEQ; j0 += 64) {
        __syncthreads();  // prev iteration's Ks/Vs/Ps readers done
        *(bf16x8*)(&Ks[sr][sc]) = kr;
        *(bf16x8*)(&Vs[sr][sc]) = vr;
        __syncthreads();

        // issue next tile's loads; land during compute
        if (j0 + 64 < SEQ) {
            kr = *(const bf16x8*)(k_g + (size_t)(j0 + 64 + sr) * QKV_LD + sc);
            vr = *(const bf16x8*)(vt_g + (size_t)sr * VT_LD + j0 + 64 + sc);
        }

        // --- QK: S^T quarter [32 j][32 i], 4 chained k-steps ---
        f32x16 st = {};
#pragma unroll
        for (int ks = 0; ks < 4; ks++) {
            bf16x8 ka = *(const bf16x8*)(&Ks[jh * 32 + l32][ks * 16 + hi * 8]);
            st = MFMA32(ka, qa[ks], st);
        }

        // --- P = exp2(st), mask (first two j-blocks carry the diagonal) ---
        if (j0 < i0 + 128) {
            int gi = i0 + ih * 32 + l32;
#pragma unroll
            for (int rq = 0; rq < 4; rq++) {
                bf16x4 pk;
#pragma unroll
                for (int r = 0; r < 4; r++) {
                    int gj = j0 + jh * 32 + 8 * rq + 4 * hi + r;
                    float p = (gj >= gi) ? __builtin_amdgcn_exp2f(st[rq * 4 + r]) : 0.0f;
                    lsum += p;
                    pk[r] = (bf16_t)p;
                }
                *(bf16x4*)(&Ps[ih * 32 + l32][jh * 32 + 8 * rq + 4 * hi]) = pk;
            }
        } else {
#pragma unroll
            for (int rq = 0; rq < 4; rq++) {
                bf16x4 pk;
#pragma unroll
                for (int r = 0; r < 4; r++) {
                    float p = __builtin_amdgcn_exp2f(st[rq * 4 + r]);
                    lsum += p;
                    pk[r] = (bf16_t)p;
                }
                *(bf16x4*)(&Ps[ih * 32 + l32][jh * 32 + 8 * rq + 4 * hi]) = pk;
            }
        }
        __syncthreads();  // Ps complete across waves

        // --- PV: O quarter [32 i][32 d] over 64 j (4 k-steps) ---
#pragma unroll
        for (int ks = 0; ks < 4; ks++) {
            bf16x8 pa = *(const bf16x8*)(&Ps[ih * 32 + l32][ks * 16 + hi * 8]);
            bf16x8 vb = *(const bf16x8*)(&Vs[jh * 32 + l32][ks * 16 + hi * 8]);
            o = MFMA32(pa, vb, o);
        }
    }

    // --- epilogue: combine row sums (lane pairs, then jh pairs via LDS) ---
    lsum += __shfl_xor(lsum, 32, 64);
    lsumS[wave][l32] = lsum;  // lanes l and l+32 write same value
    __syncthreads();

#pragma unroll
    for (int rq = 0; rq < 4; rq++) {
#pragma unroll
        for (int r = 0; r < 4; r++) {
            int il = 8 * rq + 4 * hi + r;                 // local i of this reg
            float rs = lsumS[ih * 2][il] + lsumS[ih * 2 + 1][il];  // both jh
            int gi = i0 + ih * 32 + il;
            attn_out[(size_t)(b * SEQ + gi) * HID + h * HD + jh * 32 + l32] =
                (bf16_t)(o[rq * 4 + r] / rs);
        }
    }
}

// ---------------------------------------------------------------------------
extern "C" void kernel_launch(void* const* d_in, const int* in_sizes, int n_in,
                              void* d_out, int out_size, void* d_ws, size_t ws_size,
                              hipStream_t stream) {
    const float* x     = (const float*)d_in[0];
    const float* w_qkv = (const float*)d_in[1];
    const float* b_qkv = (const float*)d_in[2];
    const float* w_out = (const float*)d_in[3];
    const float* b_out = (const float*)d_in[4];
    float* out = (float*)d_out;

    char* ws = (char*)d_ws;
    bf16_t* xbf   = (bf16_t*)(ws);               // 8.39 MB; dead after QKV GEMM
    bf16_t* wqkvT = (bf16_t*)(ws + 8388608);     // 6.29 MB
    bf16_t* woutT = (bf16_t*)(ws + 14680064);    // 2.10 MB
    bf16_t* qkv   = (bf16_t*)(ws + 16777216);    // 25.17 MB (V third unused)
    bf16_t* attn  = (bf16_t*)(ws + 41943040);    // 8.39 MB
    bf16_t* Vt    = (bf16_t*)(ws + 50331648);    // 8.52 MB; written by QKV GEMM

    prep_kernel<<<8192, 256, 0, stream>>>(x, w_qkv, w_out, xbf, wqkvT, woutT);

    // 256^2 8-phase QKV GEMM (V tiles fused-transposed into Vt): grid 192
    gemm_qkv_8ph<<<192, 512, 0, stream>>>(xbf, wqkvT, b_qkv, qkv, Vt,
                                          4096, 3072, 1024);

    attn_kernel<<<dim3(2 * NHEAD, SEQ / 128), 512, 0, stream>>>(qkv, Vt, attn);

    gemm_bt_bias<float, 64><<<dim3(1024 / 64, 4096 / 128), 256, 0, stream>>>(
        attn, woutT, b_out, out, 4096, 1024, 1024);
}